// Round 1
// baseline (48.564 us; speedup 1.0000x reference)
//
#include <hip/hip_runtime.h>

#define B_SZ 4
#define T_SEQ 1024
#define D_MODEL 256
#define H_HEADS 4

typedef __attribute__((ext_vector_type(8))) short s16x8;
typedef __attribute__((ext_vector_type(4))) float f32x4v;

__device__ __forceinline__ unsigned short f2bf(float x) {
    union { float f; unsigned int u; } v; v.f = x;
    unsigned int r = v.u + 0x7FFFu + ((v.u >> 16) & 1u);
    return (unsigned short)(r >> 16);
}

// ---------------- cvt: f32 -> bf16 for x and the 4 weight matrices ----------------
__global__ __launch_bounds__(256) void cvt_kernel(
    const float* __restrict__ x,
    const float* __restrict__ wq, const float* __restrict__ wk,
    const float* __restrict__ wv, const float* __restrict__ wo,
    unsigned short* __restrict__ xb, unsigned short* __restrict__ wb)
{
    const int NX4 = (B_SZ * T_SEQ * D_MODEL) / 4;   // 262144
    const int NW4 = (D_MODEL * D_MODEL) / 4;        // 16384
    int i4 = blockIdx.x * 256 + threadIdx.x;        // grid sized exactly
    if (i4 < NX4) {
        float4 v = ((const float4*)x)[i4];
        unsigned short* d = xb + i4 * 4;
        d[0] = f2bf(v.x); d[1] = f2bf(v.y); d[2] = f2bf(v.z); d[3] = f2bf(v.w);
    } else {
        int r = i4 - NX4;
        int m = r / NW4;
        int o = r - m * NW4;
        const float* w = (m == 0) ? wq : (m == 1) ? wk : (m == 2) ? wv : wo;
        float4 v = ((const float4*)w)[o];
        unsigned short* d = wb + m * (D_MODEL * D_MODEL) + o * 4;
        d[0] = f2bf(v.x); d[1] = f2bf(v.y); d[2] = f2bf(v.z); d[3] = f2bf(v.w);
    }
}

// ---------------- fused QKV GEMM: Y = scale*(x @ W^T + b), bf16 out ----------------
// grid (64, 12): by>>2 selects q/k/v, (by&3)*64 is the column tile. 64x64 tile/block.
__global__ __launch_bounds__(256) void gemm_qkv(
    const unsigned short* __restrict__ xb, const unsigned short* __restrict__ wb,
    const float* __restrict__ bq, const float* __restrict__ bk, const float* __restrict__ bv,
    unsigned short* __restrict__ qb, unsigned short* __restrict__ kb, unsigned short* __restrict__ vb)
{
    const int lane = threadIdx.x & 63;
    const int w    = threadIdx.x >> 6;
    const int l15  = lane & 15, hi = lane >> 4;
    const int row0 = blockIdx.x * 64;
    const int mat  = blockIdx.y >> 2;
    const int col0 = (blockIdx.y & 3) * 64;
    const unsigned short* W = wb + mat * (D_MODEL * D_MODEL);
    const float* bias = (mat == 0) ? bq : (mat == 1) ? bk : bv;
    unsigned short* out = (mat == 0) ? qb : (mat == 1) ? kb : vb;
    const float scale = (mat == 0) ? 0.125f : 1.0f;  // 1/sqrt(DH)=1/8 folded into q

    f32x4v acc[4] = {};
    const int arow = row0 + w * 16 + l15;
    #pragma unroll
    for (int kt = 0; kt < 8; ++kt) {
        int koff = kt * 32 + hi * 8;
        s16x8 a = *(const s16x8*)(xb + (size_t)arow * D_MODEL + koff);
        #pragma unroll
        for (int c = 0; c < 4; ++c) {
            s16x8 bf = *(const s16x8*)(W + (size_t)(col0 + c * 16 + l15) * D_MODEL + koff);
            acc[c] = __builtin_amdgcn_mfma_f32_16x16x32_bf16(a, bf, acc[c], 0, 0, 0);
        }
    }
    #pragma unroll
    for (int c = 0; c < 4; ++c) {
        int col = col0 + c * 16 + l15;
        float bs = bias[col];
        #pragma unroll
        for (int r = 0; r < 4; ++r) {
            int row = row0 + w * 16 + hi * 4 + r;
            out[(size_t)row * D_MODEL + col] = f2bf((acc[c][r] + bs) * scale);
        }
    }
}

// ---------------- O GEMM: out = ctx @ Wo^T + bo, f32 out ----------------
__global__ __launch_bounds__(256) void gemm_o(
    const unsigned short* __restrict__ ctxb, const unsigned short* __restrict__ wob,
    const float* __restrict__ bo, float* __restrict__ out)
{
    const int lane = threadIdx.x & 63;
    const int w    = threadIdx.x >> 6;
    const int l15  = lane & 15, hi = lane >> 4;
    const int row0 = blockIdx.x * 64;
    const int col0 = blockIdx.y * 64;

    f32x4v acc[4] = {};
    const int arow = row0 + w * 16 + l15;
    #pragma unroll
    for (int kt = 0; kt < 8; ++kt) {
        int koff = kt * 32 + hi * 8;
        s16x8 a = *(const s16x8*)(ctxb + (size_t)arow * D_MODEL + koff);
        #pragma unroll
        for (int c = 0; c < 4; ++c) {
            s16x8 bf = *(const s16x8*)(wob + (size_t)(col0 + c * 16 + l15) * D_MODEL + koff);
            acc[c] = __builtin_amdgcn_mfma_f32_16x16x32_bf16(a, bf, acc[c], 0, 0, 0);
        }
    }
    #pragma unroll
    for (int c = 0; c < 4; ++c) {
        int col = col0 + c * 16 + l15;
        float bs = bo[col];
        #pragma unroll
        for (int r = 0; r < 4; ++r) {
            int row = row0 + w * 16 + hi * 4 + r;
            out[(size_t)row * D_MODEL + col] = acc[c][r] + bs;
        }
    }
}

// ---------------- attention: per (64-query tile, h, b) ----------------
// S[t][r] = qn[t] . k0[jbase+r]  (r in [0,144), jbase = t0-12; OOB rows -> 0)
// then window softmax -> p, in-place 4-tap transform -> P2, ctx = P2 @ v0T.
__global__ __launch_bounds__(256) void attn_kernel(
    const unsigned short* __restrict__ qb, const unsigned short* __restrict__ kb,
    const unsigned short* __restrict__ vb,
    const float* __restrict__ shift_logits, const float* __restrict__ alibi_slope,
    unsigned short* __restrict__ ctxb)
{
    __shared__ float S[64][164];            // 41984 B
    __shared__ unsigned short v0T[64][168]; // 21504 B  (total 62 KB)

    const int tid  = threadIdx.x;
    const int lane = tid & 63;
    const int w    = tid >> 6;
    const int l15  = lane & 15, hi = lane >> 4;
    const int t0 = blockIdx.x * 64;
    const int h  = blockIdx.y;
    const int b  = blockIdx.z;
    const int jbase = t0 - 12;

    // P0: stage v0T[d][r] = v0[b, jbase+r, h*64+d] (bf16), zeros for OOB / r>=... (r in [0,160))
    for (int task = tid; task < 1280; task += 256) {
        int rr = task % 160;
        int dc = task / 160;          // 0..7, 8 dims each
        int j = jbase + rr;
        s16x8 vv = {0,0,0,0,0,0,0,0};
        if (j >= 0 && j < T_SEQ)
            vv = *(const s16x8*)(vb + ((size_t)(b * T_SEQ + j)) * D_MODEL + h * 64 + dc * 8);
        #pragma unroll
        for (int e = 0; e < 8; ++e) v0T[dc * 8 + e][rr] = (unsigned short)vv[e];
    }

    // P1: S = q . k^T via MFMA. wave w owns S rows [16w, 16w+16).
    {
        const unsigned short* qrow = qb + ((size_t)(b * T_SEQ + t0 + w * 16 + l15)) * D_MODEL + h * 64;
        s16x8 afr[2];
        afr[0] = *(const s16x8*)(qrow + hi * 8);
        afr[1] = *(const s16x8*)(qrow + 32 + hi * 8);
        #pragma unroll
        for (int c = 0; c < 9; ++c) {
            int j = jbase + c * 16 + l15;
            bool valid = (j >= 0) && (j < T_SEQ);
            f32x4v acc = {};
            #pragma unroll
            for (int kt = 0; kt < 2; ++kt) {
                s16x8 bf = {0,0,0,0,0,0,0,0};
                if (valid)
                    bf = *(const s16x8*)(kb + ((size_t)(b * T_SEQ + j)) * D_MODEL + h * 64 + kt * 32 + hi * 8);
                acc = __builtin_amdgcn_mfma_f32_16x16x32_bf16(afr[kt], bf, acc, 0, 0, 0);
            }
            #pragma unroll
            for (int r = 0; r < 4; ++r)
                S[w * 16 + hi * 4 + r][c * 16 + l15] = acc[r];
        }
    }
    __syncthreads();

    // per-head constants (redundant per thread, cheap)
    float l0 = shift_logits[h * 4 + 0], l1 = shift_logits[h * 4 + 1];
    float l2 = shift_logits[h * 4 + 2], l3 = shift_logits[h * 4 + 3];
    float mx = fmaxf(fmaxf(l0, l1), fmaxf(l2, l3));
    float s0 = expf(l0 - mx), s1 = expf(l1 - mx), s2 = expf(l2 - mx), s3 = expf(l3 - mx);
    float inv = 1.0f / (s0 + s1 + s2 + s3);
    float pi0 = s0 * inv + 1e-8f, pi1 = s1 * inv + 1e-8f;
    float pi2 = s2 * inv + 1e-8f, pi3 = s3 * inv + 1e-8f;
    float slope = alibi_slope[h];

    // Phase C: window softmax. 4 threads per query.
    const int tq = tid >> 2;      // local query
    const int g  = tid & 3;
    const int tg = t0 + tq;       // global query
    float att[16];
    #pragma unroll
    for (int u = 0; u < 16; ++u) {
        int o = g + 4 * u;
        int k = tg + o;
        if (k < T_SEQ) {
            int r0 = tq + o + 12;
            float z = pi0 * expf(S[tq][r0])     + pi1 * expf(S[tq][r0 - 4])
                    + pi2 * expf(S[tq][r0 - 8]) + pi3 * expf(S[tq][r0 - 12]);
            att[u] = logf(z) - slope * (float)o;
        } else att[u] = -1e30f;
    }
    float m = att[0];
    #pragma unroll
    for (int u = 1; u < 16; ++u) m = fmaxf(m, att[u]);
    m = fmaxf(m, __shfl_xor(m, 1));
    m = fmaxf(m, __shfl_xor(m, 2));
    float Zs = 0.0f;
    #pragma unroll
    for (int u = 0; u < 16; ++u) { att[u] = expf(att[u] - m); Zs += att[u]; }
    Zs += __shfl_xor(Zs, 1);
    Zs += __shfl_xor(Zs, 2);
    float rz = 1.0f / Zs;
    __syncthreads();              // all S reads done before overwrite

    // write p into slot (k - jbase); zero-fill edge slots [tq,tq+11] and [tq+76,tq+87]
    #pragma unroll
    for (int u = 0; u < 16; ++u) {
        int o = g + 4 * u;
        S[tq][tq + o + 12] = att[u] * rz;   // exact 0 for masked k
    }
    for (int i = g; i < 24; i += 4) {
        int slot = tq + (i < 12 ? i : i + 64);
        S[tq][slot] = 0.0f;
    }
    __syncthreads();

    // in-place P2 transform: S[tq][rj] <- sum_s p[slot rj+s], rj ascending per thread
    for (int ii = 0; ii < 41; ++ii) {
        int rj = g + 4 * ii;
        if (rj > 163) break;
        float val = 0.0f;
        if (rj >= tq && rj <= tq + 75)
            val = S[tq][rj] + S[tq][rj + 4] + S[tq][rj + 8] + S[tq][rj + 12];
        S[tq][rj] = val;
    }
    __syncthreads();

    // Phase D: ctx = P2 @ v0T (MFMA over K=160)
    {
        f32x4v acc[4] = {};
        s16x8 ap[5];
        #pragma unroll
        for (int kt = 0; kt < 5; ++kt) {
            const float* sp = &S[w * 16 + l15][kt * 32 + hi * 8];
            #pragma unroll
            for (int e = 0; e < 8; ++e) ap[kt][e] = (short)f2bf(sp[e]);
        }
        #pragma unroll
        for (int c = 0; c < 4; ++c) {
            #pragma unroll
            for (int kt = 0; kt < 5; ++kt) {
                s16x8 bv8 = *(const s16x8*)&v0T[c * 16 + l15][kt * 32 + hi * 8];
                acc[c] = __builtin_amdgcn_mfma_f32_16x16x32_bf16(ap[kt], bv8, acc[c], 0, 0, 0);
            }
        }
        #pragma unroll
        for (int c = 0; c < 4; ++c) {
            int d = c * 16 + l15;
            #pragma unroll
            for (int r = 0; r < 4; ++r) {
                int row = t0 + w * 16 + hi * 4 + r;
                ctxb[((size_t)(b * T_SEQ + row)) * D_MODEL + h * 64 + d] = f2bf(acc[c][r]);
            }
        }
    }
}

extern "C" void kernel_launch(void* const* d_in, const int* in_sizes, int n_in,
                              void* d_out, int out_size, void* d_ws, size_t ws_size,
                              hipStream_t stream) {
    const float* x  = (const float*)d_in[0];
    const float* Wq = (const float*)d_in[1];
    const float* bq = (const float*)d_in[2];
    const float* Wk = (const float*)d_in[3];
    const float* bk = (const float*)d_in[4];
    const float* Wv = (const float*)d_in[5];
    const float* bv = (const float*)d_in[6];
    const float* Wo = (const float*)d_in[7];
    const float* bo = (const float*)d_in[8];
    const float* shift_logits = (const float*)d_in[9];
    const float* alibi_slope  = (const float*)d_in[10];
    float* out = (float*)d_out;

    char* ws = (char*)d_ws;
    unsigned short* xb  = (unsigned short*)(ws);                              // 2 MB
    unsigned short* wb  = (unsigned short*)(ws + (2u << 20));                 // 512 KB (q,k,v,o)
    unsigned short* qb  = (unsigned short*)(ws + (2u << 20) + (512u << 10));  // 2 MB
    unsigned short* kb  = qb + (1u << 20);                                    // 2 MB
    unsigned short* vb  = kb + (1u << 20);                                    // 2 MB
    unsigned short* ctx = vb + (1u << 20);                                    // 2 MB

    cvt_kernel<<<dim3(1280), dim3(256), 0, stream>>>(x, Wq, Wk, Wv, Wo, xb, wb);
    gemm_qkv<<<dim3(64, 12), dim3(256), 0, stream>>>(xb, wb, bq, bk, bv, qb, kb, vb);
    attn_kernel<<<dim3(16, 4, 4), dim3(256), 0, stream>>>(qb, kb, vb, shift_logits, alibi_slope, ctx);
    gemm_o<<<dim3(64, 4), dim3(256), 0, stream>>>(ctx, wb + 3 * (D_MODEL * D_MODEL), bo, out);
}